// Round 1
// baseline (2526.734 us; speedup 1.0000x reference)
//
#include <hip/hip_runtime.h>
#include <cstdint>
#include <cstddef>

#define BB 8
#define NN 8192
#define CC 64
#define MM 2048
#define KK 32

__device__ __forceinline__ float sqdist_exact(float x, float y, float z,
                                              float cx, float cy, float cz) {
    // Replicate numpy/JAX f32: (x-c)**2 summed ((dx2+dy2)+dz2), no FMA contraction.
    float dx = __fsub_rn(x, cx);
    float dy = __fsub_rn(y, cy);
    float dz = __fsub_rn(z, cz);
    return __fadd_rn(__fadd_rn(__fmul_rn(dx, dx), __fmul_rn(dy, dy)),
                     __fmul_rn(dz, dz));
}

// ---------------- FPS: one block per batch, 512 threads, 16 pts/thread ----------------
__global__ __launch_bounds__(512) void fps_kernel(const float* __restrict__ x,
                                                  int* __restrict__ fps_idx) {
    const int b = blockIdx.x;
    const int tid = threadIdx.x;
    const int lane = tid & 63;
    const int wv = tid >> 6;
    const float* xb = x + (size_t)b * 3 * NN;

    float px[16], py[16], pz[16], dist[16];
#pragma unroll
    for (int p = 0; p < 16; ++p) {
        int i = tid + p * 512;
        px[p] = xb[i];
        py[p] = xb[NN + i];
        pz[p] = xb[2 * NN + i];
        dist[p] = INFINITY;
    }

    __shared__ unsigned long long red[2][8];
    int far = 0;
    for (int t = 0; t < MM; ++t) {
        if (tid == 0) fps_idx[b * MM + t] = far;
        int fu = __builtin_amdgcn_readfirstlane(far);
        float cx = xb[fu];
        float cy = xb[NN + fu];
        float cz = xb[2 * NN + fu];

        float maxv = -1.0f;
        int maxi = 0;
#pragma unroll
        for (int p = 0; p < 16; ++p) {
            float d = sqdist_exact(px[p], py[p], pz[p], cx, cy, cz);
            float nd = fminf(dist[p], d);
            dist[p] = nd;
            if (nd > maxv) { maxv = nd; maxi = tid + p * 512; }  // ascending idx + strict > => first-max
        }
        // pack (value, ~idx): max => largest value, then smallest index (first occurrence)
        unsigned long long key =
            ((unsigned long long)__float_as_uint(maxv) << 32) | (unsigned)(~(unsigned)maxi);
#pragma unroll
        for (int off = 32; off >= 1; off >>= 1) {
            unsigned long long other = __shfl_xor(key, off, 64);
            if (other > key) key = other;
        }
        if (lane == 0) red[t & 1][wv] = key;
        __syncthreads();
        unsigned long long best = red[t & 1][0];
#pragma unroll
        for (int j = 1; j < 8; ++j) {
            unsigned long long o2 = red[t & 1][j];
            if (o2 > best) best = o2;
        }
        far = (int)(~(unsigned)(best & 0xffffffffull));
    }
}

// ---------------- transform: g[b][n][o] = sum_c W[o][c] * f[b][c][n] ----------------
__global__ __launch_bounds__(256) void transform_kernel(const float* __restrict__ feature,
                                                        const float* __restrict__ weight,
                                                        float* __restrict__ g) {
    __shared__ float Wl[64 * 64];
    const int tid = threadIdx.x;
    for (int k = tid; k < 64 * 64; k += 256) Wl[k] = weight[k];
    __syncthreads();

    const int P = blockIdx.x * 256 + tid;  // global point slot
    const int b = P >> 13;                 // / 8192
    const int n = P & (NN - 1);
    const float* fb = feature + (size_t)b * CC * NN + n;

    float fr[64];
#pragma unroll
    for (int c = 0; c < 64; ++c) fr[c] = fb[(size_t)c * NN];

    float* go = g + ((size_t)b << 19) + (size_t)n * 64;
    for (int o = 0; o < 64; o += 4) {
        const float* w0 = &Wl[o * 64];
        const float* w1 = w0 + 64;
        const float* w2 = w0 + 128;
        const float* w3 = w0 + 192;
        float a0 = 0.f, a1 = 0.f, a2 = 0.f, a3 = 0.f;
#pragma unroll
        for (int c = 0; c < 64; c += 4) {
            float4 v0 = *(const float4*)(w0 + c);
            float4 v1 = *(const float4*)(w1 + c);
            float4 v2 = *(const float4*)(w2 + c);
            float4 v3 = *(const float4*)(w3 + c);
            a0 += v0.x * fr[c] + v0.y * fr[c + 1] + v0.z * fr[c + 2] + v0.w * fr[c + 3];
            a1 += v1.x * fr[c] + v1.y * fr[c + 1] + v1.z * fr[c + 2] + v1.w * fr[c + 3];
            a2 += v2.x * fr[c] + v2.y * fr[c + 1] + v2.z * fr[c + 2] + v2.w * fr[c + 3];
            a3 += v3.x * fr[c] + v3.y * fr[c + 1] + v3.z * fr[c + 2] + v3.w * fr[c + 3];
        }
        float4 r;
        r.x = a0; r.y = a1; r.z = a2; r.w = a3;
        *(float4*)(go + o) = r;
    }
}

// ---------------- ball query: one wave per query; also emits x_out (coord max) ----------------
__global__ __launch_bounds__(256) void bq_kernel(const float* __restrict__ x,
                                                 const int* __restrict__ fps_idx,
                                                 int* __restrict__ sub_idx,
                                                 float* __restrict__ xout) {
    const float R2 = (float)(0.4 * 0.4);  // match python double product -> f32 cast
    int gw = (int)((blockIdx.x * 256 + threadIdx.x) >> 6);
    const int lane = threadIdx.x & 63;
    gw = __builtin_amdgcn_readfirstlane(gw);
    const int b = gw >> 11;
    const int m = gw & (MM - 1);
    const float* xb = x + (size_t)b * 3 * NN;

    const int ctr = fps_idx[gw];
    const float cx = xb[ctr];
    const float cy = xb[NN + ctr];
    const float cz = xb[2 * NN + ctr];

    int* sid = sub_idx + (size_t)gw * KK;
    int found = 0;
    int first = 0;
    float mx = -INFINITY, my = -INFINITY, mz = -INFINITY;

    for (int base = 0; base < NN; base += 64) {
        const int i = base + lane;
        const float xx = xb[i];
        const float yy = xb[NN + i];
        const float zz = xb[2 * NN + i];
        const float d2 = sqdist_exact(xx, yy, zz, cx, cy, cz);
        const bool q = d2 < R2;
        const unsigned long long mask = __ballot(q);
        if (q) {
            int pos = found + (int)__popcll(mask & ((1ull << lane) - 1ull));
            if (pos < KK) {
                sid[pos] = i;
                mx = fmaxf(mx, xx);
                my = fmaxf(my, yy);
                mz = fmaxf(mz, zz);
            }
        }
        if (found == 0 && mask != 0ull) first = base + (int)__builtin_ctzll(mask);
        found += (int)__popcll(mask);
        if (found >= KK) break;
    }
    if (found < KK) {
        if (lane < KK - found) sid[found + lane] = first;  // pad with first found index
    }
#pragma unroll
    for (int off = 32; off >= 1; off >>= 1) {
        mx = fmaxf(mx, __shfl_xor(mx, off, 64));
        my = fmaxf(my, __shfl_xor(my, off, 64));
        mz = fmaxf(mz, __shfl_xor(mz, off, 64));
    }
    if (lane == 0) {
        xout[(size_t)b * 3 * MM + 0 * MM + m] = mx;
        xout[(size_t)b * 3 * MM + 1 * MM + m] = my;
        xout[(size_t)b * 3 * MM + 2 * MM + m] = mz;
    }
}

// ---------------- gather-max: f_out[b][o][m] = max_j g[b][idx_j][o] ----------------
__global__ __launch_bounds__(256) void gather_kernel(const float* __restrict__ g,
                                                     const int* __restrict__ sub_idx,
                                                     float* __restrict__ fout) {
    int gw = (int)((blockIdx.x * 256 + threadIdx.x) >> 6);
    const int lane = threadIdx.x & 63;
    gw = __builtin_amdgcn_readfirstlane(gw);
    const int b = gw >> 11;
    const int m = gw & (MM - 1);
    const int* sid = sub_idx + (size_t)gw * KK;
    const float* gb = g + ((size_t)b << 19);
    float acc = -INFINITY;
#pragma unroll
    for (int j = 0; j < KK; ++j) {
        const int id = sid[j];
        acc = fmaxf(acc, gb[(size_t)id * 64 + lane]);
    }
    fout[((size_t)b << 17) + ((size_t)lane << 11) + m] = acc;
}

extern "C" void kernel_launch(void* const* d_in, const int* in_sizes, int n_in,
                              void* d_out, int out_size, void* d_ws, size_t ws_size,
                              hipStream_t stream) {
    const float* x = (const float*)d_in[0];        // (8,3,8192)
    const float* feature = (const float*)d_in[1];  // (8,64,8192)
    const float* weight = (const float*)d_in[2];   // (64,64)
    // d_in[3] = num_pool (=2048), hard-coded as MM

    float* out = (float*)d_out;
    float* xout = out;                  // (8,3,2048)
    float* fout = out + BB * 3 * MM;    // (8,64,2048)

    char* ws = (char*)d_ws;
    int* fps_idx = (int*)ws;                                       // 64 KB
    int* sub_idx = (int*)(ws + (size_t)BB * MM * 4);               // 2 MB
    float* g = (float*)(ws + (size_t)BB * MM * 4 + (size_t)BB * MM * KK * 4);  // 16 MB

    fps_kernel<<<BB, 512, 0, stream>>>(x, fps_idx);
    transform_kernel<<<(BB * NN) / 256, 256, 0, stream>>>(feature, weight, g);
    bq_kernel<<<(BB * MM * 64) / 256, 256, 0, stream>>>(x, fps_idx, sub_idx, xout);
    gather_kernel<<<(BB * MM * 64) / 256, 256, 0, stream>>>(g, sub_idx, fout);
}

// Round 3
// 2043.048 us; speedup vs baseline: 1.2367x; 1.2367x over previous
//
#include <hip/hip_runtime.h>
#include <cstdint>
#include <cstddef>

#define BB 8
#define NN 8192
#define CC 64
#define MM 2048
#define KK 32

typedef float vfloat2 __attribute__((ext_vector_type(2)));

__device__ __forceinline__ float sqdist_exact(float x, float y, float z,
                                              float cx, float cy, float cz) {
    // Replicate numpy/JAX f32: (x-c)**2 summed ((dx2+dy2)+dz2), no FMA contraction.
    float dx = __fsub_rn(x, cx);
    float dy = __fsub_rn(y, cy);
    float dz = __fsub_rn(z, cz);
    return __fadd_rn(__fadd_rn(__fmul_rn(dx, dx), __fmul_rn(dy, dy)),
                     __fmul_rn(dz, dz));
}

// ---- DPP-based wave64 max-reduce of a u64 key (VALU pipe, not LDS pipe) ----
// row_shr:N = 0x110|N, row_bcast15 = 0x142, row_bcast31 = 0x143.
// bound_ctrl=true -> invalid source lanes read 0; all our keys are > 0, so 0 never wins.
template <int CTRL>
__device__ __forceinline__ unsigned long long dpp_max_u64(unsigned long long key) {
    int lo = (int)(unsigned)key;
    int hi = (int)(unsigned)(key >> 32);
    int slo = __builtin_amdgcn_update_dpp(0, lo, CTRL, 0xF, 0xF, true);
    int shi = __builtin_amdgcn_update_dpp(0, hi, CTRL, 0xF, 0xF, true);
    unsigned long long o = ((unsigned long long)(unsigned)shi << 32) | (unsigned)slo;
    return o > key ? o : key;
}

// ---------------- FPS: one block per batch, 512 threads, 16 pts/thread (8 float2) ----------------
__global__ __launch_bounds__(512) void fps_kernel(const float* __restrict__ x,
                                                  int* __restrict__ fps_idx) {
#pragma clang fp contract(off)
    const int b = blockIdx.x;
    const int tid = threadIdx.x;
    const int lane = tid & 63;
    const int wv = tid >> 6;
    const float* xb = x + (size_t)b * 3 * NN;

    __shared__ float sx[NN];
    __shared__ float sy[NN];
    __shared__ float sz[NN];
    __shared__ unsigned long long red2[2][8];

    const vfloat2* gx = (const vfloat2*)xb;
    const vfloat2* gy = (const vfloat2*)(xb + NN);
    const vfloat2* gz = (const vfloat2*)(xb + 2 * NN);

    vfloat2 px[8], py[8], pz[8], dist[8];
#pragma unroll
    for (int p = 0; p < 8; ++p) {
        const int e = tid + p * 512;  // float2 slot; covers points 2e, 2e+1
        px[p] = gx[e];
        py[p] = gy[e];
        pz[p] = gz[e];
        ((vfloat2*)sx)[e] = px[p];
        ((vfloat2*)sy)[e] = py[p];
        ((vfloat2*)sz)[e] = pz[p];
        dist[p] = (vfloat2){INFINITY, INFINITY};
    }
    __syncthreads();

    int far = 0;
    for (int t = 0; t < MM; ++t) {
        if (tid == 0) fps_idx[b * MM + t] = far;
        // centroid via LDS broadcast reads (short, parallel latency)
        const float cx = sx[far];
        const float cy = sy[far];
        const float cz = sz[far];
        const vfloat2 cx2 = {cx, cx};
        const vfloat2 cy2 = {cy, cy};
        const vfloat2 cz2 = {cz, cz};

        float maxv = -1.0f;
        int maxi = 0;
#pragma unroll
        for (int p = 0; p < 8; ++p) {
            vfloat2 dx = px[p] - cx2;
            vfloat2 dy = py[p] - cy2;
            vfloat2 dz = pz[p] - cz2;
            vfloat2 m1 = dx * dx;
            vfloat2 m2 = dy * dy;
            vfloat2 m3 = dz * dz;
            vfloat2 s = (m1 + m2) + m3;
            vfloat2 nd;
            nd.x = fminf(dist[p].x, s.x);
            nd.y = fminf(dist[p].y, s.y);
            dist[p] = nd;
            const int i0 = 2 * (tid + p * 512);
            // ascending index order + strict '>' => first-occurrence argmax
            if (nd.x > maxv) { maxv = nd.x; maxi = i0; }
            if (nd.y > maxv) { maxv = nd.y; maxi = i0 + 1; }
        }
        // pack (value, ~idx): max => largest value, ties -> smallest index
        unsigned long long key =
            ((unsigned long long)__float_as_uint(maxv) << 32) | (unsigned)(~(unsigned)maxi);
        key = dpp_max_u64<0x111>(key);  // row_shr:1
        key = dpp_max_u64<0x112>(key);  // row_shr:2
        key = dpp_max_u64<0x114>(key);  // row_shr:4
        key = dpp_max_u64<0x118>(key);  // row_shr:8
        key = dpp_max_u64<0x142>(key);  // row_bcast15
        key = dpp_max_u64<0x143>(key);  // row_bcast31 -> lane 63 has wave max
        if (lane == 63) red2[t & 1][wv] = key;
        __syncthreads();
        unsigned long long best = red2[t & 1][0];
#pragma unroll
        for (int j = 1; j < 8; ++j) {
            unsigned long long o2 = red2[t & 1][j];
            if (o2 > best) best = o2;
        }
        far = (int)(~(unsigned)best);
    }
}

// ---------------- transform: g[b][n][o] = sum_c W[o][c] * f[b][c][n] ----------------
__global__ __launch_bounds__(256) void transform_kernel(const float* __restrict__ feature,
                                                        const float* __restrict__ weight,
                                                        float* __restrict__ g) {
    __shared__ float Wl[64 * 64];
    const int tid = threadIdx.x;
    for (int k = tid; k < 64 * 64; k += 256) Wl[k] = weight[k];
    __syncthreads();

    const int P = blockIdx.x * 256 + tid;  // global point slot
    const int b = P >> 13;                 // / 8192
    const int n = P & (NN - 1);
    const float* fb = feature + (size_t)b * CC * NN + n;

    float fr[64];
#pragma unroll
    for (int c = 0; c < 64; ++c) fr[c] = fb[(size_t)c * NN];

    float* go = g + ((size_t)b << 19) + (size_t)n * 64;
    for (int o = 0; o < 64; o += 4) {
        const float* w0 = &Wl[o * 64];
        const float* w1 = w0 + 64;
        const float* w2 = w0 + 128;
        const float* w3 = w0 + 192;
        float a0 = 0.f, a1 = 0.f, a2 = 0.f, a3 = 0.f;
#pragma unroll
        for (int c = 0; c < 64; c += 4) {
            float4 v0 = *(const float4*)(w0 + c);
            float4 v1 = *(const float4*)(w1 + c);
            float4 v2 = *(const float4*)(w2 + c);
            float4 v3 = *(const float4*)(w3 + c);
            a0 += v0.x * fr[c] + v0.y * fr[c + 1] + v0.z * fr[c + 2] + v0.w * fr[c + 3];
            a1 += v1.x * fr[c] + v1.y * fr[c + 1] + v1.z * fr[c + 2] + v1.w * fr[c + 3];
            a2 += v2.x * fr[c] + v2.y * fr[c + 1] + v2.z * fr[c + 2] + v2.w * fr[c + 3];
            a3 += v3.x * fr[c] + v3.y * fr[c + 1] + v3.z * fr[c + 2] + v3.w * fr[c + 3];
        }
        float4 r;
        r.x = a0; r.y = a1; r.z = a2; r.w = a3;
        *(float4*)(go + o) = r;
    }
}

// ---------------- ball query: one wave per query; also emits x_out (coord max) ----------------
__global__ __launch_bounds__(256) void bq_kernel(const float* __restrict__ x,
                                                 const int* __restrict__ fps_idx,
                                                 int* __restrict__ sub_idx,
                                                 float* __restrict__ xout) {
    const float R2 = (float)(0.4 * 0.4);  // match python double product -> f32 cast
    int gw = (int)((blockIdx.x * 256 + threadIdx.x) >> 6);
    const int lane = threadIdx.x & 63;
    gw = __builtin_amdgcn_readfirstlane(gw);
    const int b = gw >> 11;
    const int m = gw & (MM - 1);
    const float* xb = x + (size_t)b * 3 * NN;

    const int ctr = fps_idx[gw];
    const float cx = xb[ctr];
    const float cy = xb[NN + ctr];
    const float cz = xb[2 * NN + ctr];

    int* sid = sub_idx + (size_t)gw * KK;
    int found = 0;
    int first = 0;
    float mx = -INFINITY, my = -INFINITY, mz = -INFINITY;

    for (int base = 0; base < NN; base += 64) {
        const int i = base + lane;
        const float xx = xb[i];
        const float yy = xb[NN + i];
        const float zz = xb[2 * NN + i];
        const float d2 = sqdist_exact(xx, yy, zz, cx, cy, cz);
        const bool q = d2 < R2;
        const unsigned long long mask = __ballot(q);
        if (q) {
            int pos = found + (int)__popcll(mask & ((1ull << lane) - 1ull));
            if (pos < KK) {
                sid[pos] = i;
                mx = fmaxf(mx, xx);
                my = fmaxf(my, yy);
                mz = fmaxf(mz, zz);
            }
        }
        if (found == 0 && mask != 0ull) first = base + (int)__builtin_ctzll(mask);
        found += (int)__popcll(mask);
        if (found >= KK) break;
    }
    if (found < KK) {
        if (lane < KK - found) sid[found + lane] = first;  // pad with first found index
    }
#pragma unroll
    for (int off = 32; off >= 1; off >>= 1) {
        mx = fmaxf(mx, __shfl_xor(mx, off, 64));
        my = fmaxf(my, __shfl_xor(my, off, 64));
        mz = fmaxf(mz, __shfl_xor(mz, off, 64));
    }
    if (lane == 0) {
        xout[(size_t)b * 3 * MM + 0 * MM + m] = mx;
        xout[(size_t)b * 3 * MM + 1 * MM + m] = my;
        xout[(size_t)b * 3 * MM + 2 * MM + m] = mz;
    }
}

// ---------------- gather-max: f_out[b][o][m] = max_j g[b][idx_j][o] ----------------
__global__ __launch_bounds__(256) void gather_kernel(const float* __restrict__ g,
                                                     const int* __restrict__ sub_idx,
                                                     float* __restrict__ fout) {
    int gw = (int)((blockIdx.x * 256 + threadIdx.x) >> 6);
    const int lane = threadIdx.x & 63;
    gw = __builtin_amdgcn_readfirstlane(gw);
    const int b = gw >> 11;
    const int m = gw & (MM - 1);
    const int* sid = sub_idx + (size_t)gw * KK;
    const float* gb = g + ((size_t)b << 19);
    float acc = -INFINITY;
#pragma unroll
    for (int j = 0; j < KK; ++j) {
        const int id = sid[j];
        acc = fmaxf(acc, gb[(size_t)id * 64 + lane]);
    }
    fout[((size_t)b << 17) + ((size_t)lane << 11) + m] = acc;
}

extern "C" void kernel_launch(void* const* d_in, const int* in_sizes, int n_in,
                              void* d_out, int out_size, void* d_ws, size_t ws_size,
                              hipStream_t stream) {
    const float* x = (const float*)d_in[0];        // (8,3,8192)
    const float* feature = (const float*)d_in[1];  // (8,64,8192)
    const float* weight = (const float*)d_in[2];   // (64,64)
    // d_in[3] = num_pool (=2048), hard-coded as MM

    float* out = (float*)d_out;
    float* xout = out;                  // (8,3,2048)
    float* fout = out + BB * 3 * MM;    // (8,64,2048)

    char* ws = (char*)d_ws;
    int* fps_idx = (int*)ws;                                       // 64 KB
    int* sub_idx = (int*)(ws + (size_t)BB * MM * 4);               // 2 MB
    float* g = (float*)(ws + (size_t)BB * MM * 4 + (size_t)BB * MM * KK * 4);  // 16 MB

    fps_kernel<<<BB, 512, 0, stream>>>(x, fps_idx);
    transform_kernel<<<(BB * NN) / 256, 256, 0, stream>>>(feature, weight, g);
    bq_kernel<<<(BB * MM * 64) / 256, 256, 0, stream>>>(x, fps_idx, sub_idx, xout);
    gather_kernel<<<(BB * MM * 64) / 256, 256, 0, stream>>>(g, sub_idx, fout);
}

// Round 4
// 2030.755 us; speedup vs baseline: 1.2442x; 1.0061x over previous
//
#include <hip/hip_runtime.h>
#include <cstdint>
#include <cstddef>

#define BB 8
#define NN 8192
#define CC 64
#define MM 2048
#define KK 32

typedef float vfloat2 __attribute__((ext_vector_type(2)));

__device__ __forceinline__ float sqdist_exact(float x, float y, float z,
                                              float cx, float cy, float cz) {
    // Replicate numpy/JAX f32: (x-c)**2 summed ((dx2+dy2)+dz2), no FMA contraction.
    float dx = __fsub_rn(x, cx);
    float dy = __fsub_rn(y, cy);
    float dz = __fsub_rn(z, cz);
    return __fadd_rn(__fadd_rn(__fmul_rn(dx, dx), __fmul_rn(dy, dy)),
                     __fmul_rn(dz, dz));
}

// ---- DPP-based wave64 max-reduce of a u64 key (VALU pipe, not LDS pipe) ----
// row_shr:N = 0x110|N, row_bcast15 = 0x142, row_bcast31 = 0x143.
// bound_ctrl=true -> invalid source lanes read 0; all our keys are > 0, so 0 never wins.
template <int CTRL>
__device__ __forceinline__ unsigned long long dpp_max_u64(unsigned long long key) {
    int lo = (int)(unsigned)key;
    int hi = (int)(unsigned)(key >> 32);
    int slo = __builtin_amdgcn_update_dpp(0, lo, CTRL, 0xF, 0xF, true);
    int shi = __builtin_amdgcn_update_dpp(0, hi, CTRL, 0xF, 0xF, true);
    unsigned long long o = ((unsigned long long)(unsigned)shi << 32) | (unsigned)slo;
    return o > key ? o : key;
}

// ---------------- FPS: one block per batch, 512 threads, 16 pts/thread (8 float2) ----------------
__global__ __launch_bounds__(512) void fps_kernel(const float* __restrict__ x,
                                                  int* __restrict__ fps_idx) {
#pragma clang fp contract(off)
    const int b = blockIdx.x;
    const int tid = threadIdx.x;
    const int lane = tid & 63;
    const int wv = tid >> 6;
    const float* xb = x + (size_t)b * 3 * NN;
    int* fps_store = fps_idx + b * MM;

    __shared__ float sx[NN];
    __shared__ float sy[NN];
    __shared__ float sz[NN];
    __shared__ unsigned long long red2[2][8];

    const vfloat2* gx = (const vfloat2*)xb;
    const vfloat2* gy = (const vfloat2*)(xb + NN);
    const vfloat2* gz = (const vfloat2*)(xb + 2 * NN);

    vfloat2 px[8], py[8], pz[8], dist[8];
#pragma unroll
    for (int p = 0; p < 8; ++p) {
        const int e = tid + p * 512;  // float2 slot; covers points 2e, 2e+1
        px[p] = gx[e];
        py[p] = gy[e];
        pz[p] = gz[e];
        ((vfloat2*)sx)[e] = px[p];
        ((vfloat2*)sy)[e] = py[p];
        ((vfloat2*)sz)[e] = pz[p];
        dist[p] = (vfloat2){INFINITY, INFINITY};
    }
    __syncthreads();

    int far = 0;
    for (int t = 0; t < MM; ++t) {
        if (tid == 0) fps_store[t] = far;
        // centroid via LDS broadcast reads (short, parallel latency)
        const float cx = sx[far];
        const float cy = sy[far];
        const float cz = sz[far];
        const vfloat2 cx2 = {cx, cx};
        const vfloat2 cy2 = {cy, cy};
        const vfloat2 cz2 = {cz, cz};

        // Pass 1: update dist and track running max value only (v_max3_f32).
        float maxv = -1.0f;
#pragma unroll
        for (int p = 0; p < 8; ++p) {
            vfloat2 dx = px[p] - cx2;
            vfloat2 dy = py[p] - cy2;
            vfloat2 dz = pz[p] - cz2;
            vfloat2 m1 = dx * dx;
            vfloat2 m2 = dy * dy;
            vfloat2 m3 = dz * dz;
            vfloat2 s = (m1 + m2) + m3;
            vfloat2 nd;
            nd.x = fminf(dist[p].x, s.x);
            nd.y = fminf(dist[p].y, s.y);
            dist[p] = nd;
            maxv = fmaxf(fmaxf(maxv, nd.x), nd.y);  // -> v_max3_f32
        }
        // Pass 2: descending equality re-scan => smallest index achieving maxv.
        // (maxv is the exact max of these register values, so >=1 element matches.)
        int maxi = 0;
#pragma unroll
        for (int p = 7; p >= 0; --p) {
            const int i0 = 2 * (tid + p * 512);
            if (dist[p].y == maxv) maxi = i0 + 1;
            if (dist[p].x == maxv) maxi = i0;
        }
        // pack (value, ~idx): max => largest value, ties -> smallest index
        unsigned long long key =
            ((unsigned long long)__float_as_uint(maxv) << 32) | (unsigned)(~(unsigned)maxi);
        key = dpp_max_u64<0x111>(key);  // row_shr:1
        key = dpp_max_u64<0x112>(key);  // row_shr:2
        key = dpp_max_u64<0x114>(key);  // row_shr:4
        key = dpp_max_u64<0x118>(key);  // row_shr:8
        key = dpp_max_u64<0x142>(key);  // row_bcast15
        key = dpp_max_u64<0x143>(key);  // row_bcast31 -> lane 63 has wave max
        if (lane == 63) red2[t & 1][wv] = key;
        __syncthreads();
        unsigned long long best = red2[t & 1][0];
#pragma unroll
        for (int j = 1; j < 8; ++j) {
            unsigned long long o2 = red2[t & 1][j];
            if (o2 > best) best = o2;
        }
        far = (int)(~(unsigned)best);
    }
}

// ---------------- transform: g[b][n][o] = sum_c W[o][c] * f[b][c][n] ----------------
__global__ __launch_bounds__(256) void transform_kernel(const float* __restrict__ feature,
                                                        const float* __restrict__ weight,
                                                        float* __restrict__ g) {
    __shared__ float Wl[64 * 64];
    const int tid = threadIdx.x;
    for (int k = tid; k < 64 * 64; k += 256) Wl[k] = weight[k];
    __syncthreads();

    const int P = blockIdx.x * 256 + tid;  // global point slot
    const int b = P >> 13;                 // / 8192
    const int n = P & (NN - 1);
    const float* fb = feature + (size_t)b * CC * NN + n;

    float fr[64];
#pragma unroll
    for (int c = 0; c < 64; ++c) fr[c] = fb[(size_t)c * NN];

    float* go = g + ((size_t)b << 19) + (size_t)n * 64;
    for (int o = 0; o < 64; o += 4) {
        const float* w0 = &Wl[o * 64];
        const float* w1 = w0 + 64;
        const float* w2 = w0 + 128;
        const float* w3 = w0 + 192;
        float a0 = 0.f, a1 = 0.f, a2 = 0.f, a3 = 0.f;
#pragma unroll
        for (int c = 0; c < 64; c += 4) {
            float4 v0 = *(const float4*)(w0 + c);
            float4 v1 = *(const float4*)(w1 + c);
            float4 v2 = *(const float4*)(w2 + c);
            float4 v3 = *(const float4*)(w3 + c);
            a0 += v0.x * fr[c] + v0.y * fr[c + 1] + v0.z * fr[c + 2] + v0.w * fr[c + 3];
            a1 += v1.x * fr[c] + v1.y * fr[c + 1] + v1.z * fr[c + 2] + v1.w * fr[c + 3];
            a2 += v2.x * fr[c] + v2.y * fr[c + 1] + v2.z * fr[c + 2] + v2.w * fr[c + 3];
            a3 += v3.x * fr[c] + v3.y * fr[c + 1] + v3.z * fr[c + 2] + v3.w * fr[c + 3];
        }
        float4 r;
        r.x = a0; r.y = a1; r.z = a2; r.w = a3;
        *(float4*)(go + o) = r;
    }
}

// ---------------- ball query: one wave per query; also emits x_out (coord max) ----------------
__global__ __launch_bounds__(256) void bq_kernel(const float* __restrict__ x,
                                                 const int* __restrict__ fps_idx,
                                                 int* __restrict__ sub_idx,
                                                 float* __restrict__ xout) {
    const float R2 = (float)(0.4 * 0.4);  // match python double product -> f32 cast
    int gw = (int)((blockIdx.x * 256 + threadIdx.x) >> 6);
    const int lane = threadIdx.x & 63;
    gw = __builtin_amdgcn_readfirstlane(gw);
    const int b = gw >> 11;
    const int m = gw & (MM - 1);
    const float* xb = x + (size_t)b * 3 * NN;

    const int ctr = fps_idx[gw];
    const float cx = xb[ctr];
    const float cy = xb[NN + ctr];
    const float cz = xb[2 * NN + ctr];

    int* sid = sub_idx + (size_t)gw * KK;
    int found = 0;
    int first = 0;
    float mx = -INFINITY, my = -INFINITY, mz = -INFINITY;

    for (int base = 0; base < NN; base += 64) {
        const int i = base + lane;
        const float xx = xb[i];
        const float yy = xb[NN + i];
        const float zz = xb[2 * NN + i];
        const float d2 = sqdist_exact(xx, yy, zz, cx, cy, cz);
        const bool q = d2 < R2;
        const unsigned long long mask = __ballot(q);
        if (q) {
            int pos = found + (int)__popcll(mask & ((1ull << lane) - 1ull));
            if (pos < KK) {
                sid[pos] = i;
                mx = fmaxf(mx, xx);
                my = fmaxf(my, yy);
                mz = fmaxf(mz, zz);
            }
        }
        if (found == 0 && mask != 0ull) first = base + (int)__builtin_ctzll(mask);
        found += (int)__popcll(mask);
        if (found >= KK) break;
    }
    if (found < KK) {
        if (lane < KK - found) sid[found + lane] = first;  // pad with first found index
    }
#pragma unroll
    for (int off = 32; off >= 1; off >>= 1) {
        mx = fmaxf(mx, __shfl_xor(mx, off, 64));
        my = fmaxf(my, __shfl_xor(my, off, 64));
        mz = fmaxf(mz, __shfl_xor(mz, off, 64));
    }
    if (lane == 0) {
        xout[(size_t)b * 3 * MM + 0 * MM + m] = mx;
        xout[(size_t)b * 3 * MM + 1 * MM + m] = my;
        xout[(size_t)b * 3 * MM + 2 * MM + m] = mz;
    }
}

// ---------------- gather-max: f_out[b][o][m] = max_j g[b][idx_j][o] ----------------
__global__ __launch_bounds__(256) void gather_kernel(const float* __restrict__ g,
                                                     const int* __restrict__ sub_idx,
                                                     float* __restrict__ fout) {
    int gw = (int)((blockIdx.x * 256 + threadIdx.x) >> 6);
    const int lane = threadIdx.x & 63;
    gw = __builtin_amdgcn_readfirstlane(gw);
    const int b = gw >> 11;
    const int m = gw & (MM - 1);
    const int* sid = sub_idx + (size_t)gw * KK;
    const float* gb = g + ((size_t)b << 19);
    float acc = -INFINITY;
#pragma unroll
    for (int j = 0; j < KK; ++j) {
        const int id = sid[j];
        acc = fmaxf(acc, gb[(size_t)id * 64 + lane]);
    }
    fout[((size_t)b << 17) + ((size_t)lane << 11) + m] = acc;
}

extern "C" void kernel_launch(void* const* d_in, const int* in_sizes, int n_in,
                              void* d_out, int out_size, void* d_ws, size_t ws_size,
                              hipStream_t stream) {
    const float* x = (const float*)d_in[0];        // (8,3,8192)
    const float* feature = (const float*)d_in[1];  // (8,64,8192)
    const float* weight = (const float*)d_in[2];   // (64,64)
    // d_in[3] = num_pool (=2048), hard-coded as MM

    float* out = (float*)d_out;
    float* xout = out;                  // (8,3,2048)
    float* fout = out + BB * 3 * MM;    // (8,64,2048)

    char* ws = (char*)d_ws;
    int* fps_idx = (int*)ws;                                       // 64 KB
    int* sub_idx = (int*)(ws + (size_t)BB * MM * 4);               // 2 MB
    float* g = (float*)(ws + (size_t)BB * MM * 4 + (size_t)BB * MM * KK * 4);  // 16 MB

    fps_kernel<<<BB, 512, 0, stream>>>(x, fps_idx);
    transform_kernel<<<(BB * NN) / 256, 256, 0, stream>>>(feature, weight, g);
    bq_kernel<<<(BB * MM * 64) / 256, 256, 0, stream>>>(x, fps_idx, sub_idx, xout);
    gather_kernel<<<(BB * MM * 64) / 256, 256, 0, stream>>>(g, sub_idx, fout);
}